// Round 4
// baseline (264.595 us; speedup 1.0000x reference)
//
#include <hip/hip_runtime.h>
#include <math.h>

#define BB   512
#define NN   512
#define MM   128
#define CC   1024
#define ADDR 134
#define EPSF 1e-8f
#define WSSTRIDE 136                 // region A: per-b 128 k + 8 params
#define EOFF  131072                 // region B: e[b][n], BB*NN floats
#define POFF  (EOFF + BB * NN)       // region C: partial sums, BB*4 floats

__device__ __forceinline__ float softplus_f(float x) {
    return fmaxf(x, 0.0f) + log1pf(expf(-fabsf(x)));
}

// ---------------- kernel 1: fc + derived scalar params ----------------
__global__ __launch_bounds__(192) void ntm_fc_kernel(
    const float* __restrict__ co,     // B x C
    const float* __restrict__ W_fc,   // C x ADDR
    const float* __restrict__ b_fc,   // ADDR
    float* __restrict__ ws)           // region A
{
    __shared__ __align__(16) float s_co[2 * CC];
    __shared__ float s_nr[2][2];
    __shared__ float s_ex[2][8];

    const int t = threadIdx.x;
    const int b0 = blockIdx.x * 2;

    {
        const float4* src = (const float4*)(co + (size_t)b0 * CC);
        float4* dst = (float4*)s_co;
        for (int i = t; i < 512; i += 192) dst[i] = src[i];
    }
    __syncthreads();

    float k0 = 0.f, k1 = 0.f;
    if (t < ADDR) {
        float a00 = 0.f, a01 = 0.f, a10 = 0.f, a11 = 0.f;
        const float* Wj = W_fc + t;
        for (int c = 0; c < CC; c += 8) {
            float wv[8];
            #pragma unroll
            for (int i = 0; i < 8; ++i) wv[i] = Wj[(size_t)(c + i) * ADDR];
            #pragma unroll
            for (int i = 0; i < 8; ++i) {
                if (i & 1) { a01 = fmaf(wv[i], s_co[c + i], a01);
                             a11 = fmaf(wv[i], s_co[CC + c + i], a11); }
                else       { a00 = fmaf(wv[i], s_co[c + i], a00);
                             a10 = fmaf(wv[i], s_co[CC + c + i], a10); }
            }
        }
        float bias = b_fc[t];
        k0 = a00 + a01 + bias;
        k1 = a10 + a11 + bias;
        if (t >= MM) { s_ex[0][t - MM] = k0; s_ex[1][t - MM] = k1; }
        else {
            ws[(size_t)b0 * WSSTRIDE + t] = k0;
            ws[(size_t)(b0 + 1) * WSSTRIDE + t] = k1;
        }
    }
    if (t < MM) {
        float v0 = k0 * k0, v1 = k1 * k1;
        #pragma unroll
        for (int off = 32; off >= 1; off >>= 1) {
            v0 += __shfl_xor(v0, off, 64);
            v1 += __shfl_xor(v1, off, 64);
        }
        if ((t & 63) == 0) { s_nr[t >> 6][0] = v0; s_nr[t >> 6][1] = v1; }
    }
    __syncthreads();
    if (t < 2) {
        float ks = s_nr[0][t] + s_nr[1][t];
        float norm_k = sqrtf(ks) + EPSF;
        float beta = softplus_f(s_ex[t][0]);
        float g = 1.0f / (1.0f + expf(-s_ex[t][1]));
        float e0 = s_ex[t][2], e1 = s_ex[t][3], e2 = s_ex[t][4];
        float mx = fmaxf(e0, fmaxf(e1, e2));
        float x0 = expf(e0 - mx), x1 = expf(e1 - mx), x2 = expf(e2 - mx);
        float inv = 1.0f / (x0 + x1 + x2);
        float* p = ws + (size_t)(b0 + t) * WSSTRIDE + MM;
        p[0] = beta / norm_k;
        p[1] = g;
        p[2] = x0 * inv;
        p[3] = x1 * inv;
        p[4] = x2 * inv;
        p[5] = 1.0f + softplus_f(s_ex[t][5]);
    }
}

// ---------------- kernel 2: e = exp(beta * cosine sim), pure streaming ----
// 2048 blocks x 256 threads; block (b, rc) handles rows [rc*128, rc*128+128)
__global__ __launch_bounds__(256) void ntm_sim_kernel(
    const float* __restrict__ mem,    // B x N x M
    float* __restrict__ ws)
{
    __shared__ __align__(16) float s_k[MM];
    __shared__ float s_red[4];
    __shared__ float s_bnk;

    const int t = threadIdx.x;
    const int bid = blockIdx.x;
    const int b = bid >> 2;
    const int rc = bid & 3;

    if (t < MM) s_k[t] = ws[(size_t)b * WSSTRIDE + t];
    if (t == MM) s_bnk = ws[(size_t)b * WSSTRIDE + MM];
    __syncthreads();

    const int l4 = t & 3;             // quarter-row lane
    const int r  = t >> 2;            // 0..63
    float4 kf[8];
    #pragma unroll
    for (int i = 0; i < 8; ++i) kf[i] = ((const float4*)s_k)[l4 + 4 * i];
    const float bnk = s_bnk;
    const float4* memb = (const float4*)(mem + (size_t)b * NN * MM);

    float esum = 0.f;
    #pragma unroll
    for (int it = 0; it < 2; ++it) {
        const int row = rc * 128 + it * 64 + r;
        const float4* rp = memb + (size_t)row * 32;
        float4 a[8];
        #pragma unroll
        for (int i = 0; i < 8; ++i) a[i] = rp[l4 + 4 * i];
        float d = 0.f, q = 0.f;
        #pragma unroll
        for (int i = 0; i < 8; ++i) {
            d = fmaf(a[i].x, kf[i].x, d); q = fmaf(a[i].x, a[i].x, q);
            d = fmaf(a[i].y, kf[i].y, d); q = fmaf(a[i].y, a[i].y, q);
            d = fmaf(a[i].z, kf[i].z, d); q = fmaf(a[i].z, a[i].z, q);
            d = fmaf(a[i].w, kf[i].w, d); q = fmaf(a[i].w, a[i].w, q);
        }
        d += __shfl_xor(d, 1, 64); q += __shfl_xor(q, 1, 64);
        d += __shfl_xor(d, 2, 64); q += __shfl_xor(q, 2, 64);
        // |bnk*cos| <= beta <= ~3: exp safe without max subtraction
        float e = expf(bnk * d / (sqrtf(q) + EPSF));
        if (l4 == 0) {
            ws[EOFF + (size_t)b * NN + row] = e;
            esum += e;
        }
    }
    #pragma unroll
    for (int off = 32; off >= 1; off >>= 1) esum += __shfl_xor(esum, off, 64);
    if ((t & 63) == 0) s_red[t >> 6] = esum;
    __syncthreads();
    if (t == 0)
        ws[POFF + bid] = s_red[0] + s_red[1] + s_red[2] + s_red[3];
}

// ---------------- kernel 3: softmax finish + gate/shift/sharpen + read ----
// 512 blocks x 512 threads (one per b)
__global__ __launch_bounds__(512) void ntm_read_kernel(
    const float* __restrict__ prev_w,  // B x N
    const float* __restrict__ mem,     // B x N x M
    const float* __restrict__ ws,
    float* __restrict__ out_rv,        // B x M
    float* __restrict__ out_w)         // B x N
{
    __shared__ float s_params[8];
    __shared__ float s_wg[NN];
    __shared__ float s_w[NN];
    __shared__ float s_red[8];
    __shared__ __align__(16) float s_part[16 * MM];

    const int t = threadIdx.x;
    const int b = blockIdx.x;

    float pw = prev_w[(size_t)b * NN + t];
    float e  = ws[EOFF + (size_t)b * NN + t];
    float S  = ws[POFF + b * 4 + 0] + ws[POFF + b * 4 + 1]
             + ws[POFF + b * 4 + 2] + ws[POFF + b * 4 + 3];
    if (t < 6) s_params[t] = ws[(size_t)b * WSSTRIDE + MM + t];
    __syncthreads();

    const float g = s_params[1];
    float wg = fmaf(g, e / S, (1.0f - g) * pw);
    s_wg[t] = wg;
    __syncthreads();

    float wsv = s_params[2] * s_wg[(t + NN - 1) & (NN - 1)]
              + s_params[3] * wg
              + s_params[4] * s_wg[(t + 1) & (NN - 1)];
    float wp = powf(wsv, s_params[5]);

    float lz = wp;
    #pragma unroll
    for (int off = 32; off >= 1; off >>= 1) lz += __shfl_xor(lz, off, 64);
    if ((t & 63) == 0) s_red[t >> 6] = lz;
    __syncthreads();
    float Z = 0.f;
    #pragma unroll
    for (int i = 0; i < 8; ++i) Z += s_red[i];

    float w = wp / (Z + EPSF);
    out_w[(size_t)b * NN + t] = w;
    s_w[t] = w;
    __syncthreads();

    // streaming read: 16 groups x 32 lanes; group g rows = g + 16k, k=0..31
    {
        const int gp = t >> 5;
        const int l  = t & 31;
        const float4* memb = (const float4*)(mem + (size_t)b * NN * MM);
        float4 acc = make_float4(0.f, 0.f, 0.f, 0.f);
        for (int kk = 0; kk < 32; kk += 4) {
            const int r0 = gp + 16 * kk;
            float4 a0 = memb[(size_t)(r0      ) * 32 + l];
            float4 a1 = memb[(size_t)(r0 + 16 ) * 32 + l];
            float4 a2 = memb[(size_t)(r0 + 32 ) * 32 + l];
            float4 a3 = memb[(size_t)(r0 + 48 ) * 32 + l];
            float w0 = s_w[r0], w1 = s_w[r0 + 16], w2 = s_w[r0 + 32], w3 = s_w[r0 + 48];
            acc.x = fmaf(w0, a0.x, acc.x); acc.y = fmaf(w0, a0.y, acc.y);
            acc.z = fmaf(w0, a0.z, acc.z); acc.w = fmaf(w0, a0.w, acc.w);
            acc.x = fmaf(w1, a1.x, acc.x); acc.y = fmaf(w1, a1.y, acc.y);
            acc.z = fmaf(w1, a1.z, acc.z); acc.w = fmaf(w1, a1.w, acc.w);
            acc.x = fmaf(w2, a2.x, acc.x); acc.y = fmaf(w2, a2.y, acc.y);
            acc.z = fmaf(w2, a2.z, acc.z); acc.w = fmaf(w2, a2.w, acc.w);
            acc.x = fmaf(w3, a3.x, acc.x); acc.y = fmaf(w3, a3.y, acc.y);
            acc.z = fmaf(w3, a3.z, acc.z); acc.w = fmaf(w3, a3.w, acc.w);
        }
        *((float4*)&s_part[gp * MM + l * 4]) = acc;
        __syncthreads();
        if (t < MM) {
            float r = 0.f;
            #pragma unroll
            for (int q2 = 0; q2 < 16; ++q2) r += s_part[q2 * MM + t];
            out_rv[(size_t)b * MM + t] = r;
        }
    }
}

extern "C" void kernel_launch(void* const* d_in, const int* in_sizes, int n_in,
                              void* d_out, int out_size, void* d_ws, size_t ws_size,
                              hipStream_t stream) {
    const float* co     = (const float*)d_in[0];
    const float* prev_w = (const float*)d_in[1];
    const float* mem    = (const float*)d_in[2];
    const float* W_fc   = (const float*)d_in[3];
    const float* b_fc   = (const float*)d_in[4];
    float* out = (float*)d_out;
    float* ws  = (float*)d_ws;

    ntm_fc_kernel<<<BB / 2, 192, 0, stream>>>(co, W_fc, b_fc, ws);
    ntm_sim_kernel<<<BB * 4, 256, 0, stream>>>(mem, ws);
    ntm_read_kernel<<<BB, 512, 0, stream>>>(prev_w, mem, ws,
                                            out, out + (size_t)BB * MM);
}

// Round 5
// 255.891 us; speedup vs baseline: 1.0340x; 1.0340x over previous
//
#include <hip/hip_runtime.h>
#include <math.h>

#define BB   512
#define NN   512
#define MM   128
#define CC   1024
#define ADDR 134
#define EPSF 1e-8f
#define WSSTRIDE 136
// ws regions (floats): A: k+params per b [0, 69632)
#define EOFF  131072                 // B: e[b][n], 262144 floats
#define POFF  (EOFF + BB * NN)       // C: esum partials, 4096 floats
#define DOFF  (POFF + BB * 8)        // D: w[b][n], 262144 floats

__device__ __forceinline__ float softplus_f(float x) {
    return fmaxf(x, 0.0f) + log1pf(expf(-fabsf(x)));
}

// async global->LDS 16B per lane (wave-uniform LDS base + lane*16)
__device__ __forceinline__ void gl2lds16(const float4* g, float4* l) {
    __builtin_amdgcn_global_load_lds(
        (const __attribute__((address_space(1))) void*)g,
        (__attribute__((address_space(3))) void*)l, 16, 0, 0);
}

// ---------------- kernel 1: fc + derived scalar params (split-K x2) ------
__global__ __launch_bounds__(384) void ntm_fc_kernel(
    const float* __restrict__ co,     // B x C
    const float* __restrict__ W_fc,   // C x ADDR
    const float* __restrict__ b_fc,   // ADDR
    float* __restrict__ ws)
{
    __shared__ __align__(16) float s_co[2 * CC];
    __shared__ float s_fc[2][2][ADDR];
    __shared__ float s_nr[2][2];
    __shared__ float s_ex[2][8];

    const int t = threadIdx.x;
    const int b0 = blockIdx.x * 2;

    {
        const float4* src = (const float4*)(co + (size_t)b0 * CC);
        float4* dst = (float4*)s_co;
        for (int i = t; i < 512; i += 384) dst[i] = src[i];
    }
    __syncthreads();

    {
        const int grp = (t >= 192) ? 1 : 0;
        const int j = t - grp * 192;
        if (j < ADDR) {
            float a00 = 0.f, a01 = 0.f, a10 = 0.f, a11 = 0.f;
            const float* Wj = W_fc + j;
            const int c0 = grp * 512;
            for (int c = c0; c < c0 + 512; c += 8) {
                float wv[8];
                #pragma unroll
                for (int i = 0; i < 8; ++i) wv[i] = Wj[(size_t)(c + i) * ADDR];
                #pragma unroll
                for (int i = 0; i < 8; ++i) {
                    if (i & 1) { a01 = fmaf(wv[i], s_co[c + i], a01);
                                 a11 = fmaf(wv[i], s_co[CC + c + i], a11); }
                    else       { a00 = fmaf(wv[i], s_co[c + i], a00);
                                 a10 = fmaf(wv[i], s_co[CC + c + i], a10); }
                }
            }
            s_fc[grp][0][j] = a00 + a01;
            s_fc[grp][1][j] = a10 + a11;
        }
    }
    __syncthreads();

    float r0 = 0.f, r1 = 0.f;
    if (t < ADDR) {
        float bias = b_fc[t];
        r0 = s_fc[0][0][t] + s_fc[1][0][t] + bias;
        r1 = s_fc[0][1][t] + s_fc[1][1][t] + bias;
        if (t >= MM) { s_ex[0][t - MM] = r0; s_ex[1][t - MM] = r1; }
        else {
            ws[(size_t)b0 * WSSTRIDE + t] = r0;
            ws[(size_t)(b0 + 1) * WSSTRIDE + t] = r1;
        }
    }
    if (t < MM) {
        float v0 = r0 * r0, v1 = r1 * r1;
        #pragma unroll
        for (int off = 32; off >= 1; off >>= 1) {
            v0 += __shfl_xor(v0, off, 64);
            v1 += __shfl_xor(v1, off, 64);
        }
        if ((t & 63) == 0) { s_nr[t >> 6][0] = v0; s_nr[t >> 6][1] = v1; }
    }
    __syncthreads();
    if (t < 2) {
        float ks = s_nr[0][t] + s_nr[1][t];
        float norm_k = sqrtf(ks) + EPSF;
        float beta = softplus_f(s_ex[t][0]);
        float g = 1.0f / (1.0f + expf(-s_ex[t][1]));
        float e0 = s_ex[t][2], e1 = s_ex[t][3], e2 = s_ex[t][4];
        float mx = fmaxf(e0, fmaxf(e1, e2));
        float x0 = expf(e0 - mx), x1 = expf(e1 - mx), x2 = expf(e2 - mx);
        float inv = 1.0f / (x0 + x1 + x2);
        float* p = ws + (size_t)(b0 + t) * WSSTRIDE + MM;
        p[0] = beta / norm_k;
        p[1] = g;
        p[2] = x0 * inv;
        p[3] = x1 * inv;
        p[4] = x2 * inv;
        p[5] = 1.0f + softplus_f(s_ex[t][5]);
    }
}

// ---------------- kernel 2: e = exp(beta*cos), LDS-staged streaming ------
// grid 4096 = (b, slab of 64 rows); 256 threads
__global__ __launch_bounds__(256, 2) void ntm_sim_kernel(
    const float* __restrict__ mem,    // B x N x M
    float* __restrict__ ws)
{
    __shared__ __align__(16) float s_mem[64 * MM];   // 32 KB
    __shared__ __align__(16) float s_k[MM];
    __shared__ float s_red[4];
    __shared__ float s_bnk;

    const int t = threadIdx.x;
    const int bid = blockIdx.x;
    const int b = bid >> 3;
    const int slab = bid & 7;

    const float4* gslab = (const float4*)(mem + ((size_t)b * NN + slab * 64) * MM);
    float4* l4p = (float4*)s_mem;
    #pragma unroll
    for (int i = 0; i < 8; ++i)
        gl2lds16(gslab + i * 256 + t, l4p + i * 256 + t);

    if (t < MM) s_k[t] = ws[(size_t)b * WSSTRIDE + t];
    if (t == MM) s_bnk = ws[(size_t)b * WSSTRIDE + MM];
    __syncthreads();

    const int l4 = t & 3;
    const int row = t >> 2;           // 0..63
    const float4* k4 = (const float4*)s_k;
    float4 kf[8];
    #pragma unroll
    for (int i = 0; i < 8; ++i) kf[i] = k4[l4 + 4 * i];

    const float4* r4 = (const float4*)s_mem + (size_t)row * 32;
    float d = 0.f, q = 0.f;
    #pragma unroll
    for (int i = 0; i < 8; ++i) {
        float4 a = r4[l4 + 4 * i];
        d = fmaf(a.x, kf[i].x, d); q = fmaf(a.x, a.x, q);
        d = fmaf(a.y, kf[i].y, d); q = fmaf(a.y, a.y, q);
        d = fmaf(a.z, kf[i].z, d); q = fmaf(a.z, a.z, q);
        d = fmaf(a.w, kf[i].w, d); q = fmaf(a.w, a.w, q);
    }
    d += __shfl_xor(d, 1, 64); q += __shfl_xor(q, 1, 64);
    d += __shfl_xor(d, 2, 64); q += __shfl_xor(q, 2, 64);

    // |bnk*cos| <= beta (~3): exp safe without max subtraction
    float e = expf(s_bnk * d / (sqrtf(q) + EPSF));
    float el = (l4 == 0) ? e : 0.0f;
    if (l4 == 0) ws[EOFF + (size_t)b * NN + slab * 64 + row] = e;

    #pragma unroll
    for (int off = 32; off >= 1; off >>= 1) el += __shfl_xor(el, off, 64);
    if ((t & 63) == 0) s_red[t >> 6] = el;
    __syncthreads();
    if (t == 0) ws[POFF + bid] = s_red[0] + s_red[1] + s_red[2] + s_red[3];
}

// ---------------- kernel 3a: softmax finish + gate/shift/sharpen ---------
// 512 blocks x 512 threads; writes w to out_w + ws(D), zeros out_rv
__global__ __launch_bounds__(512) void ntm_w_kernel(
    const float* __restrict__ prev_w,  // B x N
    float* __restrict__ ws,
    float* __restrict__ out_rv,        // B x M (zeroed here)
    float* __restrict__ out_w)         // B x N
{
    __shared__ float s_params[8];
    __shared__ float s_wg[NN];
    __shared__ float s_red[8];

    const int t = threadIdx.x;
    const int b = blockIdx.x;

    float pw = prev_w[(size_t)b * NN + t];
    float e  = ws[EOFF + (size_t)b * NN + t];
    float S = 0.f;
    #pragma unroll
    for (int i = 0; i < 8; ++i) S += ws[POFF + b * 8 + i];
    if (t < 6) s_params[t] = ws[(size_t)b * WSSTRIDE + MM + t];
    __syncthreads();

    const float g = s_params[1];
    float wg = fmaf(g, e / S, (1.0f - g) * pw);
    s_wg[t] = wg;
    __syncthreads();

    float wsv = s_params[2] * s_wg[(t + NN - 1) & (NN - 1)]
              + s_params[3] * wg
              + s_params[4] * s_wg[(t + 1) & (NN - 1)];
    float wp = powf(wsv, s_params[5]);

    float lz = wp;
    #pragma unroll
    for (int off = 32; off >= 1; off >>= 1) lz += __shfl_xor(lz, off, 64);
    if ((t & 63) == 0) s_red[t >> 6] = lz;
    __syncthreads();
    float Z = 0.f;
    #pragma unroll
    for (int i = 0; i < 8; ++i) Z += s_red[i];

    float w = wp / (Z + EPSF);
    out_w[(size_t)b * NN + t] = w;
    ws[DOFF + (size_t)b * NN + t] = w;
    if (t < MM) out_rv[(size_t)b * MM + t] = 0.0f;
}

// ---------------- kernel 3b: read_vec, LDS-staged streaming --------------
// grid 4096 = (b, slab of 64 rows); 256 threads; atomicAdd combine
__global__ __launch_bounds__(256, 2) void ntm_read_kernel(
    const float* __restrict__ mem,    // B x N x M
    const float* __restrict__ ws,
    float* __restrict__ out_rv)       // B x M
{
    __shared__ __align__(16) float s_mem[64 * MM];   // 32 KB
    __shared__ float s_w[64];
    __shared__ __align__(16) float s_part[8 * MM];   // 4 KB

    const int t = threadIdx.x;
    const int bid = blockIdx.x;
    const int b = bid >> 3;
    const int slab = bid & 7;

    const float4* gslab = (const float4*)(mem + ((size_t)b * NN + slab * 64) * MM);
    float4* l4p = (float4*)s_mem;
    #pragma unroll
    for (int i = 0; i < 8; ++i)
        gl2lds16(gslab + i * 256 + t, l4p + i * 256 + t);

    if (t < 64) s_w[t] = ws[DOFF + (size_t)b * NN + slab * 64 + t];
    __syncthreads();

    const int col4 = t & 31;          // float4 column
    const int rg   = t >> 5;          // 0..7, 8 rows each
    const float4* m4 = (const float4*)s_mem;
    float4 acc = make_float4(0.f, 0.f, 0.f, 0.f);
    #pragma unroll
    for (int m = 0; m < 8; ++m) {
        const int r = rg * 8 + m;
        float wv = s_w[r];
        float4 a = m4[(size_t)r * 32 + col4];
        acc.x = fmaf(wv, a.x, acc.x);
        acc.y = fmaf(wv, a.y, acc.y);
        acc.z = fmaf(wv, a.z, acc.z);
        acc.w = fmaf(wv, a.w, acc.w);
    }
    ((float4*)s_part)[rg * 32 + col4] = acc;
    __syncthreads();
    if (t < MM) {
        float v = 0.f;
        #pragma unroll
        for (int r = 0; r < 8; ++r) v += s_part[r * MM + t];
        atomicAdd(&out_rv[(size_t)b * MM + t], v);
    }
}

extern "C" void kernel_launch(void* const* d_in, const int* in_sizes, int n_in,
                              void* d_out, int out_size, void* d_ws, size_t ws_size,
                              hipStream_t stream) {
    const float* co     = (const float*)d_in[0];
    const float* prev_w = (const float*)d_in[1];
    const float* mem    = (const float*)d_in[2];
    const float* W_fc   = (const float*)d_in[3];
    const float* b_fc   = (const float*)d_in[4];
    float* out = (float*)d_out;
    float* ws  = (float*)d_ws;
    float* out_rv = out;
    float* out_w  = out + (size_t)BB * MM;

    ntm_fc_kernel<<<BB / 2, 384, 0, stream>>>(co, W_fc, b_fc, ws);
    ntm_sim_kernel<<<BB * 8, 256, 0, stream>>>(mem, ws);
    ntm_w_kernel<<<BB, 512, 0, stream>>>(prev_w, ws, out_rv, out_w);
    ntm_read_kernel<<<BB * 8, 256, 0, stream>>>(mem, ws, out_rv);
}

// Round 6
// 242.126 us; speedup vs baseline: 1.0928x; 1.0568x over previous
//
#include <hip/hip_runtime.h>
#include <math.h>

#define BB   512
#define NN   512
#define MM   128
#define CC   1024
#define ADDR 134
#define EPSF 1e-8f

__device__ __forceinline__ float softplus_f(float x) {
    return fmaxf(x, 0.0f) + log1pf(expf(-fabsf(x)));
}

// One block per batch. 512 threads; each thread owns quarter-rows (32 floats
// each) of rows {row0, row0+128, row0+256, row0+384} => whole 256KB slab in
// the block's VGPR file. mem is read from HBM exactly once; pass 2 runs from
// registers.
__global__ __launch_bounds__(512, 2) void ntm_fused_kernel(
    const float* __restrict__ co,      // B x C
    const float* __restrict__ prev_w,  // B x N
    const float* __restrict__ mem,     // B x N x M
    const float* __restrict__ W_fc,    // C x ADDR
    const float* __restrict__ b_fc,    // ADDR
    float* __restrict__ out_rv,        // B x M
    float* __restrict__ out_w)         // B x N
{
    __shared__ __align__(16) float s_co[CC];        // 4 KB
    __shared__ float s_fcp[2][ADDR];
    __shared__ __align__(16) float s_k[MM];
    __shared__ float s_ex[8];
    __shared__ float s_params[8];
    __shared__ float s_e[NN];
    __shared__ float s_wg[NN];
    __shared__ float s_w[NN];
    __shared__ float s_red[8];
    __shared__ __align__(16) float4 s_comb[8][4][8]; // 4 KB

    const int t    = threadIdx.x;
    const int b    = blockIdx.x;
    const int wv   = t >> 6;
    const int l4   = t & 3;        // quarter-row (f4 cols l4+4i)
    const int row0 = t >> 2;       // 0..127

    // ---- register prefetch of the whole slab (32 independent f4 loads) ----
    const float4* memb = (const float4*)(mem + (size_t)b * NN * MM);
    float4 a[4][8];
    #pragma unroll
    for (int it = 0; it < 4; ++it) {
        const float4* rp = memb + (size_t)(row0 + 128 * it) * 32;
        #pragma unroll
        for (int i = 0; i < 8; ++i) a[it][i] = rp[l4 + 4 * i];
    }
    float pw = prev_w[(size_t)b * NN + t];

    // ---- stage controller row ----
    if (t < 256) ((float4*)s_co)[t] = ((const float4*)(co + (size_t)b * CC))[t];
    __syncthreads();

    // ---- fc: 268 threads, 2-way split-K over C ----
    if (t < 2 * ADDR) {
        const int grp = (t >= ADDR) ? 1 : 0;
        const int j   = t - grp * ADDR;
        const int c0  = grp << 9;
        const float* Wj = W_fc + j;
        float a0 = 0.f, a1 = 0.f, a2 = 0.f, a3 = 0.f;
        for (int c = 0; c < 512; c += 8) {
            const int cc = c0 + c;
            a0 = fmaf(Wj[(size_t)(cc + 0) * ADDR], s_co[cc + 0], a0);
            a1 = fmaf(Wj[(size_t)(cc + 1) * ADDR], s_co[cc + 1], a1);
            a2 = fmaf(Wj[(size_t)(cc + 2) * ADDR], s_co[cc + 2], a2);
            a3 = fmaf(Wj[(size_t)(cc + 3) * ADDR], s_co[cc + 3], a3);
            a0 = fmaf(Wj[(size_t)(cc + 4) * ADDR], s_co[cc + 4], a0);
            a1 = fmaf(Wj[(size_t)(cc + 5) * ADDR], s_co[cc + 5], a1);
            a2 = fmaf(Wj[(size_t)(cc + 6) * ADDR], s_co[cc + 6], a2);
            a3 = fmaf(Wj[(size_t)(cc + 7) * ADDR], s_co[cc + 7], a3);
        }
        s_fcp[grp][j] = (a0 + a1) + (a2 + a3);
    }
    __syncthreads();
    if (t < ADDR) {
        float r = s_fcp[0][t] + s_fcp[1][t] + b_fc[t];
        if (t < MM) s_k[t] = r; else s_ex[t - MM] = r;
    }
    __syncthreads();

    // ---- ||k|| + scalar params ----
    {
        float v = (t < MM) ? s_k[t] * s_k[t] : 0.f;
        #pragma unroll
        for (int off = 32; off >= 1; off >>= 1) v += __shfl_xor(v, off, 64);
        if ((t & 63) == 0) s_red[wv] = v;
    }
    __syncthreads();
    if (t == 0) {
        float ks = 0.f;
        #pragma unroll
        for (int i = 0; i < 8; ++i) ks += s_red[i];
        float norm_k = sqrtf(ks) + EPSF;
        float beta = softplus_f(s_ex[0]);
        float g = 1.0f / (1.0f + expf(-s_ex[1]));
        float e0 = s_ex[2], e1 = s_ex[3], e2 = s_ex[4];
        float mx = fmaxf(e0, fmaxf(e1, e2));
        float x0 = expf(e0 - mx), x1 = expf(e1 - mx), x2 = expf(e2 - mx);
        float inv = 1.0f / (x0 + x1 + x2);
        s_params[0] = beta / norm_k;
        s_params[1] = g;
        s_params[2] = x0 * inv;
        s_params[3] = x1 * inv;
        s_params[4] = x2 * inv;
        s_params[5] = 1.0f + softplus_f(s_ex[5]);
    }
    __syncthreads();

    // ---- pass 1: e = exp(beta*cos) from registers ----
    {
        const float bnk = s_params[0];
        float4 kf[8];
        #pragma unroll
        for (int i = 0; i < 8; ++i) kf[i] = ((const float4*)s_k)[l4 + 4 * i];
        float el = 0.f;
        #pragma unroll
        for (int it = 0; it < 4; ++it) {
            float d = 0.f, q = 0.f;
            #pragma unroll
            for (int i = 0; i < 8; ++i) {
                float4 av = a[it][i];
                d = fmaf(av.x, kf[i].x, d); q = fmaf(av.x, av.x, q);
                d = fmaf(av.y, kf[i].y, d); q = fmaf(av.y, av.y, q);
                d = fmaf(av.z, kf[i].z, d); q = fmaf(av.z, av.z, q);
                d = fmaf(av.w, kf[i].w, d); q = fmaf(av.w, av.w, q);
            }
            d += __shfl_xor(d, 1, 64); q += __shfl_xor(q, 1, 64);
            d += __shfl_xor(d, 2, 64); q += __shfl_xor(q, 2, 64);
            // |beta*cos| <= beta (~3): exp safe without max subtraction
            float e = expf(bnk * d / (sqrtf(q) + EPSF));
            if (l4 == 0) { s_e[row0 + 128 * it] = e; el += e; }
        }
        #pragma unroll
        for (int off = 32; off >= 1; off >>= 1) el += __shfl_xor(el, off, 64);
        if ((t & 63) == 0) s_red[wv] = el;
    }
    __syncthreads();

    // ---- softmax finish + gate + shift + sharpen + normalize ----
    {
        float S = 0.f;
        #pragma unroll
        for (int i = 0; i < 8; ++i) S += s_red[i];
        const float g = s_params[1];
        float wg = fmaf(g, s_e[t] / S, (1.0f - g) * pw);
        s_wg[t] = wg;
        __syncthreads();

        float wsv = s_params[2] * s_wg[(t + NN - 1) & (NN - 1)]
                  + s_params[3] * wg
                  + s_params[4] * s_wg[(t + 1) & (NN - 1)];
        float wp = powf(wsv, s_params[5]);

        float lz = wp;
        #pragma unroll
        for (int off = 32; off >= 1; off >>= 1) lz += __shfl_xor(lz, off, 64);
        if ((t & 63) == 0) s_red[wv] = lz;
        __syncthreads();
        float Z = 0.f;
        #pragma unroll
        for (int i = 0; i < 8; ++i) Z += s_red[i];

        float w = wp / (Z + EPSF);
        s_w[t] = w;
        out_w[(size_t)b * NN + t] = w;
    }
    __syncthreads();

    // ---- pass 2: read_vec from registers ----
    {
        float4 acc[8];
        #pragma unroll
        for (int i = 0; i < 8; ++i) acc[i] = make_float4(0.f, 0.f, 0.f, 0.f);
        #pragma unroll
        for (int it = 0; it < 4; ++it) {
            float wr = s_w[row0 + 128 * it];
            #pragma unroll
            for (int i = 0; i < 8; ++i) {
                float4 av = a[it][i];
                acc[i].x = fmaf(wr, av.x, acc[i].x);
                acc[i].y = fmaf(wr, av.y, acc[i].y);
                acc[i].z = fmaf(wr, av.z, acc[i].z);
                acc[i].w = fmaf(wr, av.w, acc[i].w);
            }
        }
        // butterfly across the 16 same-l4 lanes of each wave (stride 4)
        #pragma unroll
        for (int mask = 4; mask <= 32; mask <<= 1) {
            #pragma unroll
            for (int i = 0; i < 8; ++i) {
                acc[i].x += __shfl_xor(acc[i].x, mask, 64);
                acc[i].y += __shfl_xor(acc[i].y, mask, 64);
                acc[i].z += __shfl_xor(acc[i].z, mask, 64);
                acc[i].w += __shfl_xor(acc[i].w, mask, 64);
            }
        }
        if (((t >> 2) & 15) == 0) {          // lanes 0..3 of each wave
            #pragma unroll
            for (int i = 0; i < 8; ++i) s_comb[wv][l4][i] = acc[i];
        }
        __syncthreads();
        if (t < MM) {
            const int F = t >> 2, cl4 = F & 3, ii = F >> 2, comp = t & 3;
            float r = 0.f;
            #pragma unroll
            for (int w8 = 0; w8 < 8; ++w8)
                r += ((const float*)&s_comb[w8][cl4][ii])[comp];
            out_rv[(size_t)b * MM + t] = r;
        }
    }
}

extern "C" void kernel_launch(void* const* d_in, const int* in_sizes, int n_in,
                              void* d_out, int out_size, void* d_ws, size_t ws_size,
                              hipStream_t stream) {
    const float* co     = (const float*)d_in[0];
    const float* prev_w = (const float*)d_in[1];
    const float* mem    = (const float*)d_in[2];
    const float* W_fc   = (const float*)d_in[3];
    const float* b_fc   = (const float*)d_in[4];
    float* out = (float*)d_out;
    ntm_fused_kernel<<<BB, 512, 0, stream>>>(co, prev_w, mem, W_fc, b_fc,
                                             out, out + (size_t)BB * MM);
}